// Round 10
// baseline (93.244 us; speedup 1.0000x reference)
//
#include <hip/hip_runtime.h>
#include <hip/hip_bf16.h>

typedef __bf16 bf16_t;
typedef bf16_t bf16x2 __attribute__((ext_vector_type(2)));
typedef bf16_t bf16x4 __attribute__((ext_vector_type(4)));
typedef bf16_t bf16x8 __attribute__((ext_vector_type(8)));
typedef float  floatx4  __attribute__((ext_vector_type(4)));
typedef float  floatx16 __attribute__((ext_vector_type(16)));

constexpr int B = 8, N = 2048, D = 64;
constexpr int TSTR = 65;   // prepass transpose stride (fp32)

// --- prepass: 1-D grid, b = bx&7. bx>>8 selects K-convert / V-transpose ---
__global__ __launch_bounds__(256)
void prepass_kernel(const float* __restrict__ k, const float* __restrict__ v,
                    bf16_t* __restrict__ kb, bf16_t* __restrict__ vt) {
    __shared__ float t[64 * TSTR];
    const int tid = threadIdx.x;
    const int b   = blockIdx.x & 7;
    const int r0  = ((blockIdx.x >> 3) & 31) * 64;
    if ((blockIdx.x >> 8) == 0) {
        const float* src = k + ((size_t)b * N + r0) * D;
        bf16_t* dst = kb + ((size_t)b * N + r0) * D;
        #pragma unroll
        for (int p = 0; p < 4; ++p) {
            int e = (tid + p * 256) * 4;
            floatx4 f = *(const floatx4*)(src + e);
            bf16x4 o;
            #pragma unroll
            for (int j = 0; j < 4; ++j) o[j] = (bf16_t)f[j];
            *(bf16x4*)(dst + e) = o;
        }
    } else {
        const float* vb = v + ((size_t)b * N + r0) * D;
        #pragma unroll
        for (int p = 0; p < 4; ++p) {
            int e = (tid + p * 256) * 4;
            int row = e >> 6, col = e & 63;
            floatx4 f = *(const floatx4*)(vb + e);
            #pragma unroll
            for (int j = 0; j < 4; ++j) t[(col + j) * TSTR + row] = f[j];
        }
        __syncthreads();
        bf16_t* ob = vt + (size_t)b * D * N + r0;
        #pragma unroll
        for (int p = 0; p < 4; ++p) {
            int e = (tid + p * 256) * 4;
            int drow = e >> 6, kcol = e & 63;
            bf16x4 o;
            #pragma unroll
            for (int j = 0; j < 4; ++j) o[j] = (bf16_t)t[drow * TSTR + kcol + j];
            *(bf16x4*)(ob + (size_t)drow * N + kcol) = o;
        }
    }
}

// --- flash attention partials: BM=128, BN=64, kv-split=4 ---
// grid 512 = [split(4)][qblk(16)][b(8)], 512 thr = 8 waves = 4 q-groups x 2 kv-slices.
// 33 KB LDS -> 2 blocks/CU (load balance + barrier overlap). Each block stages
// its kv quarter (8 iters x 16 KB, dbuf, 1 barrier/iter) and emits an
// unnormalized O-partial (128x64 fp32) + l-partial to workspace.
__global__ __launch_bounds__(512, 4)
void attn_kernel(const float* __restrict__ q, const bf16_t* __restrict__ kb,
                 const bf16_t* __restrict__ vt, float* __restrict__ osp,
                 float* __restrict__ lsp) {
    __shared__ char smem[33280];   // dbuf 2 x (K 8KB + V 8KB); overlay o_buf 32KB + l_buf

    const int tid  = threadIdx.x;
    const int lane = tid & 63;
    const int wave = tid >> 6;
    const int qg   = wave >> 1;    // q-group: 32 q rows (BM=128)
    const int cg   = wave & 1;     // kv slice of 32 within the 64-tile
    const int h    = lane >> 5;
    const int l31  = lane & 31;
    const int sw   = l31 & 7;      // XOR-swizzle key for fragment reads

    const int b     = blockIdx.x & 7;
    const int qblk  = (blockIdx.x >> 3) & 15;
    const int split = blockIdx.x >> 7;
    const int q0 = qblk * 128 + qg * 32;
    const int kv_base = split * 512;

    const bf16_t* kbb = kb + (size_t)b * N * D;
    const bf16_t* vbb = vt + (size_t)b * D * N;

    // Q B-frags fp32->bf16: B[k=d][n=q=l31]
    bf16x8 qf[4];
    {
        const float* qp = q + ((size_t)b * N + q0 + l31) * D + h * 8;
        #pragma unroll
        for (int kd = 0; kd < 4; ++kd) {
            floatx4 f0 = *(const floatx4*)(qp + kd * 16);
            floatx4 f1 = *(const floatx4*)(qp + kd * 16 + 4);
            bf16x8 t;
            #pragma unroll
            for (int j = 0; j < 4; ++j) { t[j] = (bf16_t)f0[j]; t[j + 4] = (bf16_t)f1[j]; }
            qf[kd] = t;
        }
    }

    floatx16 o_acc[2];
    #pragma unroll
    for (int d = 0; d < 2; ++d)
        #pragma unroll
        for (int i = 0; i < 16; ++i) o_acc[d][i] = 0.f;
    float l_run = 0.f;

    // preload tile 0 (512 thr x 8 bf16 = one 64x64 tile each for K and V)
    const int e = tid * 8;             // 0..4095
    bf16x8 kreg = *(const bf16x8*)(kbb + (size_t)kv_base * D + e);
    bf16x8 vreg = *(const bf16x8*)(vbb + (size_t)(e >> 6) * N + kv_base + (e & 63));

    const int er = e >> 6, eg = (e >> 3) & 7;   // staging row / granule
    const int esw = ((eg ^ (er & 7)) << 3);

    #pragma unroll 1
    for (int it = 0; it < 8; ++it) {
        char* base = smem + (it & 1) * 16384;
        bf16_t* lds_k = (bf16_t*)base;           // [64][64] swizzled
        bf16_t* lds_v = (bf16_t*)(base + 8192);  // [64][64] swizzled

        *(bf16x8*)&lds_k[er * 64 + esw] = kreg;
        *(bf16x8*)&lds_v[er * 64 + esw] = vreg;
        __syncthreads();   // single barrier: dbuf reuse distance is 2 iters

        if (it + 1 < 8) {
            const int kv1 = kv_base + (it + 1) * 64;
            kreg = *(const bf16x8*)(kbb + (size_t)kv1 * D + e);
            vreg = *(const bf16x8*)(vbb + (size_t)(e >> 6) * N + kv1 + (e & 63));
        }

        // S^T = K Q^T (32kv x 32q)
        floatx16 s;
        #pragma unroll
        for (int i = 0; i < 16; ++i) s[i] = 0.f;
        #pragma unroll
        for (int kd = 0; kd < 4; ++kd) {
            bf16x8 kf = *(const bf16x8*)&lds_k[(cg * 32 + l31) * 64 + (((2 * kd + h) ^ sw) << 3)];
            s = __builtin_amdgcn_mfma_f32_32x32x16_bf16(kf, qf[kd], s, 0, 0, 0);
        }

        // scale + equality-mask (attn==0 -> -inf -> weight 0) + exp; pack bf16 pairs
        int q8[8];
        #pragma unroll
        for (int g = 0; g < 8; ++g) {
            union { int i; bf16x2 h2; } u;
            #pragma unroll
            for (int j = 0; j < 2; ++j) {
                float x = s[2 * g + j] * 0.125f;
                float p = (x == 0.0f) ? 0.0f : __expf(x);
                l_run += p;
                u.h2[j] = (bf16_t)p;
            }
            q8[g] = u.i;
        }

        // O^T += V^T P^T : A = Vt-frag (swizzled LDS), B = P^T-frag via half-wave exchange
        #pragma unroll
        for (int s2 = 0; s2 < 2; ++s2) {
            int r0 = __shfl_xor(q8[4 * s2 + 0], 32);
            int r1 = __shfl_xor(q8[4 * s2 + 1], 32);
            int r2 = __shfl_xor(q8[4 * s2 + 2], 32);
            int r3 = __shfl_xor(q8[4 * s2 + 3], 32);
            union { int i4[4]; bf16x8 v; } bf;
            bf.i4[0] = h ? r2 : q8[4 * s2 + 0];
            bf.i4[1] = h ? r3 : q8[4 * s2 + 1];
            bf.i4[2] = h ? q8[4 * s2 + 2] : r0;
            bf.i4[3] = h ? q8[4 * s2 + 3] : r1;
            #pragma unroll
            for (int dblk = 0; dblk < 2; ++dblk) {
                bf16x8 va = *(const bf16x8*)&lds_v[(dblk * 32 + l31) * 64 +
                                                   (((cg * 4 + s2 * 2 + h) ^ sw) << 3)];
                o_acc[dblk] = __builtin_amdgcn_mfma_f32_32x32x16_bf16(va, bf.v, o_acc[dblk], 0, 0, 0);
            }
        }
    }

    __syncthreads();   // loop LDS reads done; smem becomes o_buf / l_buf

    // complete this lane's denom (partner half-wave holds the other 16 kv rows)
    l_run += __shfl_xor(l_run, 32);

    float* o_buf = (float*)smem;             // [4 qg][64 d][32 q]
    float* l_buf = (float*)(smem + 32768);   // [4 qg][32 q]

    if (cg == 1) {
        float* ob = o_buf + qg * 2048;
        #pragma unroll
        for (int dblk = 0; dblk < 2; ++dblk)
            #pragma unroll
            for (int i = 0; i < 16; ++i) {
                const int d = (i & 3) + 8 * (i >> 2) + 4 * h + dblk * 32;
                ob[d * 32 + l31] = o_acc[dblk][i];
            }
        if (h == 0) l_buf[qg * 32 + l31] = l_run;
    }
    __syncthreads();
    if (cg == 0) {
        const float lsum = l_run + l_buf[qg * 32 + l31];
        const float* ob = o_buf + qg * 2048;
        const size_t pb = (size_t)(split * 8 + b) * 16 + qblk;   // partial-block index
        float* op = osp + (pb * 128 + qg * 32 + l31) * 64;
        #pragma unroll
        for (int dblk = 0; dblk < 2; ++dblk)
            #pragma unroll
            for (int g = 0; g < 4; ++g) {
                const int d0 = 8 * g + 4 * h + dblk * 32;
                floatx4 o4;
                #pragma unroll
                for (int j = 0; j < 4; ++j)
                    o4[j] = o_acc[dblk][4 * g + j] + ob[(d0 + j) * 32 + l31];
                *(floatx4*)(op + d0) = o4;
            }
        if (h == 0) lsp[pb * 128 + qg * 32 + l31] = lsum;
    }
}

// --- merge: sum the 4 kv-split partials, normalize, write out ---
__global__ __launch_bounds__(256)
void merge_kernel(const float* __restrict__ osp, const float* __restrict__ lsp,
                  float* __restrict__ out) {
    const int idx = blockIdx.x * 256 + threadIdx.x;   // over B*N*D = 1M
    const int b   = idx >> 17;
    const int rem = idx & 131071;
    const int qblk = rem >> 13;          // q>>7  (q = rem>>6)
    const int ql   = (rem >> 6) & 127;
    const int d    = rem & 63;
    float o = 0.f, l = 0.f;
    #pragma unroll
    for (int s = 0; s < 4; ++s) {
        const size_t pb = (size_t)(s * 8 + b) * 16 + qblk;
        o += osp[(pb * 128 + ql) * 64 + d];
        l += lsp[pb * 128 + ql];
    }
    out[idx] = o / l;
}

extern "C" void kernel_launch(void* const* d_in, const int* in_sizes, int n_in,
                              void* d_out, int out_size, void* d_ws, size_t ws_size,
                              hipStream_t stream) {
    const float* q = (const float*)d_in[0];
    const float* k = (const float*)d_in[1];
    const float* v = (const float*)d_in[2];
    float* out = (float*)d_out;
    bf16_t* kb = (bf16_t*)d_ws;                                    // 2 MB
    bf16_t* vt = (bf16_t*)((char*)d_ws + (size_t)B * N * D * 2);   // 2 MB
    float*  osp = (float*)((char*)d_ws + (4u << 20));              // 4 splits x 8 x 16 x 128 x 64 = 16.8 MB
    float*  lsp = (float*)((char*)d_ws + (24u << 20));             // 256 KB

    hipLaunchKernelGGL(prepass_kernel, dim3(512), dim3(256), 0, stream, k, v, kb, vt);
    hipLaunchKernelGGL(attn_kernel, dim3(512), dim3(512), 0, stream, q, kb, vt, osp, lsp);
    hipLaunchKernelGGL(merge_kernel, dim3((B * N * D) / 256), dim3(256), 0, stream, osp, lsp, out);
}

// Round 11
// 82.861 us; speedup vs baseline: 1.1253x; 1.1253x over previous
//
#include <hip/hip_runtime.h>
#include <hip/hip_bf16.h>

typedef __bf16 bf16_t;
typedef bf16_t bf16x2 __attribute__((ext_vector_type(2)));
typedef bf16_t bf16x8 __attribute__((ext_vector_type(8)));
typedef float  floatx4  __attribute__((ext_vector_type(4)));
typedef float  floatx16 __attribute__((ext_vector_type(16)));

constexpr int B = 8, N = 2048, D = 64;

// --- prepass: emit K and V in MFMA fragment order so the attention loop's
// loads are lane-contiguous (1KB coalesced per wave-load, no LDS staging).
// KF[b][kvblk][kd][lane][8]  = K[b][kvblk*32 + (lane&31)][kd*16 + (lane>>5)*8 + j]
// VF[b][kvblk][s2*2+dblk][lane][8] = V[b][kvblk*32 + s2*16 + (lane>>5)*8 + j][dblk*32 + (lane&31)]
// grid 512 = [kvblk(64)][b(8)], 256 thr.
__global__ __launch_bounds__(256)
void prepass_kernel(const float* __restrict__ k, const float* __restrict__ v,
                    bf16_t* __restrict__ kf, bf16_t* __restrict__ vf) {
    __shared__ float t[32 * 65];
    const int tid = threadIdx.x;
    const int b   = blockIdx.x & 7;
    const int kvb = blockIdx.x >> 3;                       // 0..63
    const size_t inoff  = ((size_t)b * N + kvb * 32) * D;  // 32x64 fp32 chunk
    const size_t outoff = (size_t)(b * 64 + kvb) * 2048;   // 4x64x8 bf16 frags

    // K: coalesced read, fragment-order 16B write
    {
        const float* src = k + inoff;
        floatx4 f0 = *(const floatx4*)(src + tid * 8);
        floatx4 f1 = *(const floatx4*)(src + tid * 8 + 4);
        bf16x8 o;
        #pragma unroll
        for (int j = 0; j < 4; ++j) { o[j] = (bf16_t)f0[j]; o[j + 4] = (bf16_t)f1[j]; }
        const int rr = tid >> 3, kd = (tid >> 1) & 3, hh = tid & 1;
        *(bf16x8*)(kf + outoff + (size_t)kd * 512 + (hh * 32 + rr) * 8) = o;
    }
    // V: coalesced read -> padded LDS tile -> transposed gather -> coalesced frag write
    {
        const float* src = v + inoff;
        floatx4 f0 = *(const floatx4*)(src + tid * 8);
        floatx4 f1 = *(const floatx4*)(src + tid * 8 + 4);
        const int rr = tid >> 3, cc = (tid & 7) * 8;
        #pragma unroll
        for (int j = 0; j < 4; ++j) { t[rr * 65 + cc + j] = f0[j]; t[rr * 65 + cc + 4 + j] = f1[j]; }
        __syncthreads();
        const int s2 = tid >> 7, dblk = (tid >> 6) & 1, lane = tid & 63;
        const int hh = lane >> 5, l31 = lane & 31;
        bf16x8 o;
        #pragma unroll
        for (int j = 0; j < 8; ++j)
            o[j] = (bf16_t)t[(s2 * 16 + hh * 8 + j) * 65 + dblk * 32 + l31];
        *(bf16x8*)(vf + outoff + (size_t)(s2 * 2 + dblk) * 512 + lane * 8) = o;
    }
}

// --- flash attention, transposed (S^T = K Q^T, O^T = V^T P^T), fragment-direct ---
// grid 512 = [qt(64)][b(8)], 512 thr = 8 kv-slice waves. NO LDS / NO barriers in
// the loop: every fragment is one coalesced 1KB wave-load from the L2-resident
// frag arrays. kf prefetched 1 iter ahead; vf issued a body ahead of its use.
// 58 KB LDS (epilogue merge only) -> 2 blocks/CU, 4 waves/SIMD.
__global__ __launch_bounds__(512, 4)
void attn_kernel(const float* __restrict__ q, const bf16_t* __restrict__ kf,
                 const bf16_t* __restrict__ vf, float* __restrict__ out) {
    __shared__ char smem[58240];             // o_buf [7][64][32] f32 + l_buf [7][32]
    float* o_buf = (float*)smem;
    float* l_buf = (float*)(smem + 57344);

    const int tid  = threadIdx.x;
    const int lane = tid & 63;
    const int cg   = tid >> 6;     // kv-slice wave: handles kvblk = it*8 + cg
    const int h    = lane >> 5;
    const int l31  = lane & 31;

    const int b  = blockIdx.x & 7;
    const int q0 = (blockIdx.x >> 3) * 32;

    const bf16_t* kfb = kf + (size_t)b * 131072;
    const bf16_t* vfb = vf + (size_t)b * 131072;

    // Q B-frags fp32->bf16: B[k=d][n=q=l31]
    bf16x8 qf[4];
    {
        const float* qp = q + ((size_t)b * N + q0 + l31) * D + h * 8;
        #pragma unroll
        for (int kd = 0; kd < 4; ++kd) {
            floatx4 f0 = *(const floatx4*)(qp + kd * 16);
            floatx4 f1 = *(const floatx4*)(qp + kd * 16 + 4);
            bf16x8 t;
            #pragma unroll
            for (int j = 0; j < 4; ++j) { t[j] = (bf16_t)f0[j]; t[j + 4] = (bf16_t)f1[j]; }
            qf[kd] = t;
        }
    }

    floatx16 o_acc[2];
    #pragma unroll
    for (int d = 0; d < 2; ++d)
        #pragma unroll
        for (int i = 0; i < 16; ++i) o_acc[d][i] = 0.f;
    float l_run = 0.f;

    // prefetch kf for it=0 (kvblk = cg)
    bf16x8 kreg[4];
    #pragma unroll
    for (int kd = 0; kd < 4; ++kd)
        kreg[kd] = *(const bf16x8*)(kfb + (size_t)cg * 2048 + kd * 512 + lane * 8);

    #pragma unroll 1
    for (int it = 0; it < 8; ++it) {
        const size_t base = (size_t)(it * 8 + cg) * 2048;

        // vf for THIS iter: issued now, consumed after QK+softmax (~300 cyc)
        bf16x8 vreg[4];
        #pragma unroll
        for (int u = 0; u < 4; ++u)
            vreg[u] = *(const bf16x8*)(vfb + base + (size_t)u * 512 + lane * 8);

        bf16x8 kcur[4];
        #pragma unroll
        for (int kd = 0; kd < 4; ++kd) kcur[kd] = kreg[kd];

        // kf for NEXT iter
        if (it + 1 < 8) {
            const size_t nbase = (size_t)((it + 1) * 8 + cg) * 2048;
            #pragma unroll
            for (int kd = 0; kd < 4; ++kd)
                kreg[kd] = *(const bf16x8*)(kfb + nbase + (size_t)kd * 512 + lane * 8);
        }

        // S^T = K Q^T (32kv x 32q)
        floatx16 s;
        #pragma unroll
        for (int i = 0; i < 16; ++i) s[i] = 0.f;
        #pragma unroll
        for (int kd = 0; kd < 4; ++kd)
            s = __builtin_amdgcn_mfma_f32_32x32x16_bf16(kcur[kd], qf[kd], s, 0, 0, 0);

        // scale + equality-mask (attn==0 -> -inf -> weight 0) + exp; pack bf16 pairs
        int q8[8];
        #pragma unroll
        for (int g = 0; g < 8; ++g) {
            union { int i; bf16x2 h2; } u;
            #pragma unroll
            for (int j = 0; j < 2; ++j) {
                float x = s[2 * g + j] * 0.125f;
                float p = (x == 0.0f) ? 0.0f : __expf(x);
                l_run += p;
                u.h2[j] = (bf16_t)p;
            }
            q8[g] = u.i;
        }

        // O^T += V^T P^T : A = V-frag (global), B = P^T-frag via half-wave exchange
        #pragma unroll
        for (int s2 = 0; s2 < 2; ++s2) {
            int r0 = __shfl_xor(q8[4 * s2 + 0], 32);
            int r1 = __shfl_xor(q8[4 * s2 + 1], 32);
            int r2 = __shfl_xor(q8[4 * s2 + 2], 32);
            int r3 = __shfl_xor(q8[4 * s2 + 3], 32);
            union { int i4[4]; bf16x8 v; } bf;
            bf.i4[0] = h ? r2 : q8[4 * s2 + 0];
            bf.i4[1] = h ? r3 : q8[4 * s2 + 1];
            bf.i4[2] = h ? q8[4 * s2 + 2] : r0;
            bf.i4[3] = h ? q8[4 * s2 + 3] : r1;
            #pragma unroll
            for (int dblk = 0; dblk < 2; ++dblk)
                o_acc[dblk] = __builtin_amdgcn_mfma_f32_32x32x16_bf16(vreg[s2 * 2 + dblk], bf.v,
                                                                      o_acc[dblk], 0, 0, 0);
        }
    }

    // complete this lane's denom (partner half-wave holds the other 16 kv rows)
    l_run += __shfl_xor(l_run, 32);

    // merge the 8 kv-slice partials (plain sums; epilogue-only LDS use)
    if (cg > 0) {
        float* ob = o_buf + (size_t)(cg - 1) * 2048;
        #pragma unroll
        for (int dblk = 0; dblk < 2; ++dblk)
            #pragma unroll
            for (int i = 0; i < 16; ++i) {
                const int d = (i & 3) + 8 * (i >> 2) + 4 * h + dblk * 32;
                ob[d * 32 + l31] = o_acc[dblk][i];
            }
        if (h == 0) l_buf[(cg - 1) * 32 + l31] = l_run;
    }
    __syncthreads();
    if (cg == 0) {
        float lsum = l_run;
        #pragma unroll
        for (int gg = 0; gg < 7; ++gg) lsum += l_buf[gg * 32 + l31];
        const float inv_l = 1.0f / lsum;
        float* op = out + ((size_t)b * N + q0 + l31) * D;
        #pragma unroll
        for (int dblk = 0; dblk < 2; ++dblk)
            #pragma unroll
            for (int g = 0; g < 4; ++g) {
                const int d0 = 8 * g + 4 * h + dblk * 32;
                floatx4 o4;
                #pragma unroll
                for (int j = 0; j < 4; ++j) {
                    float sum = o_acc[dblk][4 * g + j];
                    #pragma unroll
                    for (int gg = 0; gg < 7; ++gg)
                        sum += o_buf[(size_t)gg * 2048 + (d0 + j) * 32 + l31];
                    o4[j] = sum * inv_l;
                }
                *(floatx4*)(op + d0) = o4;
            }
    }
}

extern "C" void kernel_launch(void* const* d_in, const int* in_sizes, int n_in,
                              void* d_out, int out_size, void* d_ws, size_t ws_size,
                              hipStream_t stream) {
    const float* q = (const float*)d_in[0];
    const float* k = (const float*)d_in[1];
    const float* v = (const float*)d_in[2];
    float* out = (float*)d_out;
    bf16_t* kfrag = (bf16_t*)d_ws;                                    // 2 MB
    bf16_t* vfrag = (bf16_t*)((char*)d_ws + (size_t)B * N * D * 2);   // 2 MB

    hipLaunchKernelGGL(prepass_kernel, dim3(512), dim3(256), 0, stream, k, v, kfrag, vfrag);
    hipLaunchKernelGGL(attn_kernel, dim3(512), dim3(512), 0, stream, q, kfrag, vfrag, out);
}

// Round 12
// 82.736 us; speedup vs baseline: 1.1270x; 1.0015x over previous
//
#include <hip/hip_runtime.h>
#include <hip/hip_bf16.h>

typedef __bf16 bf16_t;
typedef bf16_t bf16x2 __attribute__((ext_vector_type(2)));
typedef bf16_t bf16x8 __attribute__((ext_vector_type(8)));
typedef float  floatx4  __attribute__((ext_vector_type(4)));
typedef float  floatx16 __attribute__((ext_vector_type(16)));

constexpr int B = 8, N = 2048, D = 64;

// --- prepass: emit K and V in MFMA fragment order so the attention loop's
// loads are lane-contiguous (1KB coalesced per wave-load, no LDS staging).
// KF[b][kvblk][kd][lane][8]  = K[b][kvblk*32 + (lane&31)][kd*16 + (lane>>5)*8 + j]
// VF[b][kvblk][s2*2+dblk][lane][8] = V[b][kvblk*32 + s2*16 + (lane>>5)*8 + j][dblk*32 + (lane&31)]
// grid 512 = [kvblk(64)][b(8)], 256 thr.
__global__ __launch_bounds__(256)
void prepass_kernel(const float* __restrict__ k, const float* __restrict__ v,
                    bf16_t* __restrict__ kf, bf16_t* __restrict__ vf) {
    __shared__ float t[32 * 65];
    const int tid = threadIdx.x;
    const int b   = blockIdx.x & 7;
    const int kvb = blockIdx.x >> 3;                       // 0..63
    const size_t inoff  = ((size_t)b * N + kvb * 32) * D;  // 32x64 fp32 chunk
    const size_t outoff = (size_t)(b * 64 + kvb) * 2048;   // 4x64x8 bf16 frags

    // K: coalesced read, fragment-order 16B write
    {
        const float* src = k + inoff;
        floatx4 f0 = *(const floatx4*)(src + tid * 8);
        floatx4 f1 = *(const floatx4*)(src + tid * 8 + 4);
        bf16x8 o;
        #pragma unroll
        for (int j = 0; j < 4; ++j) { o[j] = (bf16_t)f0[j]; o[j + 4] = (bf16_t)f1[j]; }
        const int rr = tid >> 3, kd = (tid >> 1) & 3, hh = tid & 1;
        *(bf16x8*)(kf + outoff + (size_t)kd * 512 + (hh * 32 + rr) * 8) = o;
    }
    // V: coalesced read -> padded LDS tile -> transposed gather -> coalesced frag write
    {
        const float* src = v + inoff;
        floatx4 f0 = *(const floatx4*)(src + tid * 8);
        floatx4 f1 = *(const floatx4*)(src + tid * 8 + 4);
        const int rr = tid >> 3, cc = (tid & 7) * 8;
        #pragma unroll
        for (int j = 0; j < 4; ++j) { t[rr * 65 + cc + j] = f0[j]; t[rr * 65 + cc + 4 + j] = f1[j]; }
        __syncthreads();
        const int s2 = tid >> 7, dblk = (tid >> 6) & 1, lane = tid & 63;
        const int hh = lane >> 5, l31 = lane & 31;
        bf16x8 o;
        #pragma unroll
        for (int j = 0; j < 8; ++j)
            o[j] = (bf16_t)t[(s2 * 16 + hh * 8 + j) * 65 + dblk * 32 + l31];
        *(bf16x8*)(vf + outoff + (size_t)(s2 * 2 + dblk) * 512 + lane * 8) = o;
    }
}

// --- flash attention, transposed (S^T = K Q^T, O^T = V^T P^T), fragment-direct ---
// grid 512 = [qt(64)][b(8)], 512 thr = 8 kv-slice waves. NO LDS / NO barriers in
// the loop. Q pre-scaled by 1/8 (exact pow2 -> S comes out as S/8 bitwise; the
// ==0 equality-mask semantics are unchanged). unroll 2 lets the compiler
// software-pipeline two iteration bodies (exp of i overlaps loads/MFMA of i+1).
__global__ __launch_bounds__(512, 4)
void attn_kernel(const float* __restrict__ q, const bf16_t* __restrict__ kf,
                 const bf16_t* __restrict__ vf, float* __restrict__ out) {
    __shared__ char smem[58240];             // o_buf [7][64][32] f32 + l_buf [7][32]
    float* o_buf = (float*)smem;
    float* l_buf = (float*)(smem + 57344);

    const int tid  = threadIdx.x;
    const int lane = tid & 63;
    const int cg   = tid >> 6;     // kv-slice wave: handles kvblk = it*8 + cg
    const int h    = lane >> 5;
    const int l31  = lane & 31;

    const int b  = blockIdx.x & 7;
    const int q0 = (blockIdx.x >> 3) * 32;

    const bf16_t* kfb = kf + (size_t)b * 131072;
    const bf16_t* vfb = vf + (size_t)b * 131072;

    // Q B-frags, pre-scaled by 0.125 then fp32->bf16 (exponent shift: exact)
    bf16x8 qf[4];
    {
        const float* qp = q + ((size_t)b * N + q0 + l31) * D + h * 8;
        #pragma unroll
        for (int kd = 0; kd < 4; ++kd) {
            floatx4 f0 = *(const floatx4*)(qp + kd * 16);
            floatx4 f1 = *(const floatx4*)(qp + kd * 16 + 4);
            bf16x8 t;
            #pragma unroll
            for (int j = 0; j < 4; ++j) {
                t[j]     = (bf16_t)(f0[j] * 0.125f);
                t[j + 4] = (bf16_t)(f1[j] * 0.125f);
            }
            qf[kd] = t;
        }
    }

    floatx16 o_acc[2];
    #pragma unroll
    for (int d = 0; d < 2; ++d)
        #pragma unroll
        for (int i = 0; i < 16; ++i) o_acc[d][i] = 0.f;
    float l_run = 0.f;

    // prefetch kf for it=0 (kvblk = cg)
    bf16x8 kreg[4];
    #pragma unroll
    for (int kd = 0; kd < 4; ++kd)
        kreg[kd] = *(const bf16x8*)(kfb + (size_t)cg * 2048 + kd * 512 + lane * 8);

    #pragma unroll 2
    for (int it = 0; it < 8; ++it) {
        const size_t base = (size_t)(it * 8 + cg) * 2048;

        // vf for THIS iter: issued now, consumed after QK+softmax
        bf16x8 vreg[4];
        #pragma unroll
        for (int u = 0; u < 4; ++u)
            vreg[u] = *(const bf16x8*)(vfb + base + (size_t)u * 512 + lane * 8);

        // S^T(/8) = K (Q/8)^T (32kv x 32q)
        floatx16 s;
        #pragma unroll
        for (int i = 0; i < 16; ++i) s[i] = 0.f;
        #pragma unroll
        for (int kd = 0; kd < 4; ++kd)
            s = __builtin_amdgcn_mfma_f32_32x32x16_bf16(kreg[kd], qf[kd], s, 0, 0, 0);

        // kf for NEXT iter (SSA rename handles the WAR with the MFMAs above)
        if (it + 1 < 8) {
            const size_t nbase = (size_t)((it + 1) * 8 + cg) * 2048;
            #pragma unroll
            for (int kd = 0; kd < 4; ++kd)
                kreg[kd] = *(const bf16x8*)(kfb + nbase + (size_t)kd * 512 + lane * 8);
        }

        // equality-mask (attn==0 -> -inf -> weight 0) + exp; pack bf16 pairs
        int q8[8];
        #pragma unroll
        for (int g = 0; g < 8; ++g) {
            union { int i; bf16x2 h2; } u;
            #pragma unroll
            for (int j = 0; j < 2; ++j) {
                float x = s[2 * g + j];
                float p = (x == 0.0f) ? 0.0f : __expf(x);
                l_run += p;
                u.h2[j] = (bf16_t)p;
            }
            q8[g] = u.i;
        }

        // O^T += V^T P^T : A = V-frag (global), B = P^T-frag via half-wave exchange
        #pragma unroll
        for (int s2 = 0; s2 < 2; ++s2) {
            int r0 = __shfl_xor(q8[4 * s2 + 0], 32);
            int r1 = __shfl_xor(q8[4 * s2 + 1], 32);
            int r2 = __shfl_xor(q8[4 * s2 + 2], 32);
            int r3 = __shfl_xor(q8[4 * s2 + 3], 32);
            union { int i4[4]; bf16x8 v; } bf;
            bf.i4[0] = h ? r2 : q8[4 * s2 + 0];
            bf.i4[1] = h ? r3 : q8[4 * s2 + 1];
            bf.i4[2] = h ? q8[4 * s2 + 2] : r0;
            bf.i4[3] = h ? q8[4 * s2 + 3] : r1;
            #pragma unroll
            for (int dblk = 0; dblk < 2; ++dblk)
                o_acc[dblk] = __builtin_amdgcn_mfma_f32_32x32x16_bf16(vreg[s2 * 2 + dblk], bf.v,
                                                                      o_acc[dblk], 0, 0, 0);
        }
    }

    // complete this lane's denom (partner half-wave holds the other 16 kv rows)
    l_run += __shfl_xor(l_run, 32);

    // merge the 8 kv-slice partials (plain sums; epilogue-only LDS use)
    if (cg > 0) {
        float* ob = o_buf + (size_t)(cg - 1) * 2048;
        #pragma unroll
        for (int dblk = 0; dblk < 2; ++dblk)
            #pragma unroll
            for (int i = 0; i < 16; ++i) {
                const int d = (i & 3) + 8 * (i >> 2) + 4 * h + dblk * 32;
                ob[d * 32 + l31] = o_acc[dblk][i];
            }
        if (h == 0) l_buf[(cg - 1) * 32 + l31] = l_run;
    }
    __syncthreads();
    if (cg == 0) {
        float lsum = l_run;
        #pragma unroll
        for (int gg = 0; gg < 7; ++gg) lsum += l_buf[gg * 32 + l31];
        const float inv_l = 1.0f / lsum;
        float* op = out + ((size_t)b * N + q0 + l31) * D;
        #pragma unroll
        for (int dblk = 0; dblk < 2; ++dblk)
            #pragma unroll
            for (int g = 0; g < 4; ++g) {
                const int d0 = 8 * g + 4 * h + dblk * 32;
                floatx4 o4;
                #pragma unroll
                for (int j = 0; j < 4; ++j) {
                    float sum = o_acc[dblk][4 * g + j];
                    #pragma unroll
                    for (int gg = 0; gg < 7; ++gg)
                        sum += o_buf[(size_t)gg * 2048 + (d0 + j) * 32 + l31];
                    o4[j] = sum * inv_l;
                }
                *(floatx4*)(op + d0) = o4;
            }
    }
}

extern "C" void kernel_launch(void* const* d_in, const int* in_sizes, int n_in,
                              void* d_out, int out_size, void* d_ws, size_t ws_size,
                              hipStream_t stream) {
    const float* q = (const float*)d_in[0];
    const float* k = (const float*)d_in[1];
    const float* v = (const float*)d_in[2];
    float* out = (float*)d_out;
    bf16_t* kfrag = (bf16_t*)d_ws;                                    // 2 MB
    bf16_t* vfrag = (bf16_t*)((char*)d_ws + (size_t)B * N * D * 2);   // 2 MB

    hipLaunchKernelGGL(prepass_kernel, dim3(512), dim3(256), 0, stream, k, v, kfrag, vfrag);
    hipLaunchKernelGGL(attn_kernel, dim3(512), dim3(512), 0, stream, q, kfrag, vfrag, out);
}